// Round 8
// baseline (474.714 us; speedup 1.0000x reference)
//
#include <hip/hip_runtime.h>
#include <math.h>

#define BATCH    8192
#define TSTEPS   128
#define SDIM     16
#define HID      50
#define IN0      17
#define BT       16     // samples per block = MFMA N
#define NTHREADS 448    // 7 waves

// X row layout (f16 elems), double-buffered, stride RS:
//  k 0..15: features   k16: delta (reg-injected)  k17: one (reg-injected, bias col)
//  k18..31: zero       k32..95: h0 (u0..49 real, u50=const-1 for b_1, rest 0)
//  k96..159: h1 (u0..49 real, u50=const-1 for b_fc1, rest 0)
// RS=168: 84 dwords == 20 (mod 32) -> b128 reads spread over 8 bank-groups (2-way, free).
// REGISTER BUDGET (R2/R4/R5 lessons): hard cap 128 unified VGPR (launch_bounds 448,4).
// R3 live set ~111. Spilled: +40 bias regs (R2), +32 carried frags (R4), even +16
// phase-local split accumulators (R5). NO register increases fit.
// Tripwires: FETCH>40MB or WRITE>10MB = spill.
// R5-kept: log2(e) folded into staged gate weights -> native exp2 activations (0 regs).
// R7: time loop unrolled x2 with compile-time buffer roles (LSTM_STEP(t,0,1)/(t+1,1,0))
//     so every LDS access is per-lane-base + constant ds-immediate (no pointer swap,
//     no per-access address VALU). Register-negative.
// (R7 bench was an infra failure - container died twice; this is an identical resubmit.)
#define RS      168
#define OFF_H0  32
#define OFF_H1  96
#define W0K     96      // cols: [w_ih0(17) | b_0(@17) | 0..31 | w_hh0(50)+0pad]
#define W1K     128     // cols: [w_ih1(50) | b_1(@50) | 0..63 | w_hh1(50) | 0(@50!) +pad]
#define WFK     64      // cols: [w_fc1(50) | b_fc1(@50) | 0 pad]   (FC NOT pre-scaled!)

#define LOG2E_F  1.44269504088896f

typedef _Float16 half_t;
typedef __attribute__((ext_vector_type(8))) _Float16 half8;
typedef __attribute__((ext_vector_type(4))) float    floatx4;

#define MFMA16(a, b, c) __builtin_amdgcn_mfma_f32_16x16x32_f16((a), (b), (c), 0, 0, 0)

// Gate pre-activations arrive PRE-SCALED by log2(e) (folded into staged weights),
// so sigmoid/tanh use native exp2 with no scale mul.
__device__ __forceinline__ float sig_u(float y) {    // y = x*log2e
    return __builtin_amdgcn_rcpf(1.0f + __builtin_amdgcn_exp2f(-y));
}
__device__ __forceinline__ float tanh_u(float y) {   // y = x*log2e
    return fmaf(2.0f, __builtin_amdgcn_rcpf(1.0f + __builtin_amdgcn_exp2f(-2.0f * y)), -1.0f);
}
__device__ __forceinline__ float tanh_c(float c) {   // c in normal domain (cell state)
    return fmaf(2.0f, __builtin_amdgcn_rcpf(1.0f + __builtin_amdgcn_exp2f(c * (-2.0f * LOG2E_F))), -1.0f);
}
__device__ __forceinline__ void hsplit(float v, half_t* hp, half_t* lp) {
    half_t h = (half_t)v;
    *hp = h;
    *lp = (half_t)(v - (float)h);
}

__global__ __launch_bounds__(NTHREADS, 4)   // VGPR cap 128 (unified)
void lstm2_w8_kernel(const float* __restrict__ feat,
                     const float* __restrict__ w_ih0,
                     const float* __restrict__ w_hh0,
                     const float* __restrict__ b_0,
                     const float* __restrict__ w_ih1,
                     const float* __restrict__ w_hh1,
                     const float* __restrict__ b_1,
                     const float* __restrict__ w_fc1,
                     const float* __restrict__ b_fc1,
                     const float* __restrict__ w_fc2,
                     const float* __restrict__ b_fc2,
                     float* __restrict__ out)
{
    __shared__ __align__(16) half_t smW[64 * W1K];               // 16 KB chunk scratch
    __shared__ __align__(16) half_t Xh[2][BT * RS];              // 10.5 KB
    __shared__ __align__(16) half_t Xl[2][BT * RS];              // 10.5 KB  (~38 KB total)

    const int tid  = threadIdx.x;
    const int lane = tid & 63;
    const int wv   = tid >> 6;          // 0..6; wave w owns M-tiles {2w, 2w+1} (13 real tiles)
    const int quad = lane >> 4;
    const int col  = lane & 15;
    const int k0q  = quad * 8;
    const int b0   = blockIdx.x * BT;
    const int tcnt = (wv < 6) ? 2 : 1;  // wave 6 owns 1 real tile (rows 192..207); rows>=200 zero

    // Unit-interleaved rows: row 4j+q = gate q (i,f,g,o) of unit j; orig = q*50+j. Rows>=200 zero.
    auto w0val = [&](int r, int k) -> float {
        if (r >= 200) return 0.0f;
        int j = r >> 2, q = r & 3, orig = q * HID + j;
        if (k < IN0)  return w_ih0[orig * IN0 + k];
        if (k == IN0) return b_0[orig];                       // bias via x const-1 @k17
        if (k < OFF_H0) return 0.0f;
        int u = k - OFF_H0;
        return (u < HID) ? w_hh0[orig * HID + u] : 0.0f;      // h0-pad cols (incl u50) zero
    };
    auto w1val = [&](int r, int k) -> float {
        if (r >= 200) return 0.0f;
        int j = r >> 2, q = r & 3, orig = q * HID + j;
        if (k < 64) {
            if (k < HID)  return w_ih1[orig * HID + k];       // x h0
            if (k == HID) return b_1[orig];                   // bias via h0 const-1 slot
            return 0.0f;
        }
        int u = k - 64;                                       // x h1; u50 stays 0 (protects FC const-1)
        return (u < HID) ? w_hh1[orig * HID + u] : 0.0f;
    };

    // ---- stage weights through 16KB scratch, 64-row chunks; waves {2c,2c+1} grab frags of chunk c
    //      Gate weights (incl bias + delta cols) pre-scaled by log2(e) for exp2 activations.
    half8 a0f[3][2], a1f[4][2];
    const int lbase = 32 * (wv & 1) + col;
    #pragma unroll 1
    for (int c = 0; c < 4; ++c) {
        for (int i = tid; i < 64 * W0K; i += NTHREADS) {
            int r = i / W0K, k = i - r * W0K;
            smW[i] = (half_t)(w0val(64 * c + r, k) * LOG2E_F);
        }
        __syncthreads();
        if ((wv >> 1) == c) {
            #pragma unroll
            for (int kt = 0; kt < 3; ++kt)
                #pragma unroll
                for (int ti = 0; ti < 2; ++ti)
                    a0f[kt][ti] = *(const half8*)(smW + (lbase + 16 * ti) * W0K + 32 * kt + k0q);
        }
        __syncthreads();
    }
    #pragma unroll 1
    for (int c = 0; c < 4; ++c) {
        for (int i = tid; i < 64 * W1K; i += NTHREADS) {
            int r = i >> 7, k = i & 127;
            smW[i] = (half_t)(w1val(64 * c + r, k) * LOG2E_F);
        }
        __syncthreads();
        if ((wv >> 1) == c) {
            #pragma unroll
            for (int kt = 0; kt < 4; ++kt)
                #pragma unroll
                for (int ti = 0; ti < 2; ++ti)
                    a1f[kt][ti] = *(const half8*)(smW + (lbase + 16 * ti) * W1K + 32 * kt + k0q);
        }
        __syncthreads();
    }
    // Wf (32x64): rows 0..24 real, col 50 = b_fc1. NOT scaled (linear/ReLU path).
    for (int i = tid; i < 32 * WFK; i += NTHREADS) {
        int r = i >> 6, k = i & 63;
        float v = 0.0f;
        if (r < 25) { if (k < HID) v = w_fc1[r * HID + k]; else if (k == HID) v = b_fc1[r]; }
        smW[i] = (half_t)v;
    }
    __syncthreads();
    half8 wff[2][2];
    #pragma unroll
    for (int kt = 0; kt < 2; ++kt)
        #pragma unroll
        for (int tf = 0; tf < 2; ++tf)
            wff[kt][tf] = *(const half8*)(smW + (16 * tf + col) * WFK + 32 * kt + k0q);

    // ---- X buffers: zero, then const-1 slots + t=0 features (barrier between)
    for (int i = tid; i < BT * RS; i += NTHREADS) {
        Xh[0][i] = (half_t)0.0f; Xl[0][i] = (half_t)0.0f;
        Xh[1][i] = (half_t)0.0f; Xl[1][i] = (half_t)0.0f;
    }
    __syncthreads();
    if (tid < BT) {   // const-1 slots (hi=1, lo=0) in BOTH buffers; never overwritten (u<50 store guard)
        Xh[0][tid * RS + OFF_H0 + HID] = (half_t)1.0f;
        Xh[1][tid * RS + OFF_H0 + HID] = (half_t)1.0f;
        Xh[0][tid * RS + OFF_H1 + HID] = (half_t)1.0f;
        Xh[1][tid * RS + OFF_H1 + HID] = (half_t)1.0f;
    }
    const bool stager = (tid < BT * SDIM);                // 256 feature loaders (waves 0-3)
    const int  xs = tid >> 4, xk = tid & 15;
    const size_t fbase = (size_t)(b0 + (stager ? xs : 0)) * (TSTEPS * SDIM) + xk;
    if (stager) hsplit(feat[fbase], &Xh[0][xs * RS + xk], &Xl[0][xs * RS + xk]);

    // ---- per-lane FC output consts (all waves: FC is computed redundantly everywhere)
    floatx4 w2r[2];
    { floatx4 z = {0.f, 0.f, 0.f, 0.f}; w2r[0] = z; w2r[1] = z; }
    #pragma unroll
    for (int tf = 0; tf < 2; ++tf)
        #pragma unroll
        for (int r5 = 0; r5 < 4; ++r5) {
            int r = 16 * tf + 4 * quad + r5;
            if (r < 25) w2r[tf][r5] = w_fc2[r];
        }
    const float bf2 = b_fc2[0];

    const half8   hz = {0, 0, 0, 0, 0, 0, 0, 0};
    const floatx4 fz = {0.f, 0.f, 0.f, 0.f};
    float c0s[2] = {0.f, 0.f};
    float c1s[2] = {0.f, 0.f};
    half_t dh = (half_t)0.0f, dl = (half_t)0.0f;   // prev_delta hi/lo (reg-resident)
    floatx4 accf[2]; accf[0] = fz; accf[1] = fz;   // FC accumulator, carried across loop edge

    __syncthreads();

// One timestep. CUR/NXT are LITERAL 0/1 -> every LDS access below compiles to
// (per-lane base col*RS*2) + constant immediate. No pointer swap, no addr VALU.
#define LSTM_STEP(T, CUR, NXT)                                                         \
    {                                                                                  \
        float fnext = 0.0f;                                                            \
        if (stager && ((T) + 1 < TSTEPS)) fnext = feat[fbase + (size_t)((T) + 1) * SDIM]; \
        /* P1a: layer-0 gates, h0 contribution (kt=1,2) - independent of prev delta */ \
        floatx4 acc[2]; acc[0] = fz; acc[1] = fz;                                      \
        _Pragma("unroll")                                                              \
        for (int kt = 1; kt < 3; ++kt) {                                               \
            half8 bh = *(const half8*)(&Xh[CUR][col * RS + OFF_H0 + 32 * (kt - 1) + k0q]); \
            half8 bl = *(const half8*)(&Xl[CUR][col * RS + OFF_H0 + 32 * (kt - 1) + k0q]); \
            _Pragma("unroll")                                                          \
            for (int ti = 0; ti < 2; ++ti)                                             \
                if (ti < tcnt) {                                                       \
                    acc[ti] = MFMA16(a0f[kt][ti], bh, acc[ti]);                        \
                    acc[ti] = MFMA16(a0f[kt][ti], bl, acc[ti]);                        \
                }                                                                      \
        }                                                                              \
        /* deferred FC reduce of step T-1 (rotated across the loop edge) */            \
        if ((T) > 0) {                                                                 \
            float p = 0.0f;                                                            \
            _Pragma("unroll")                                                          \
            for (int tf = 0; tf < 2; ++tf)                                             \
                _Pragma("unroll")                                                      \
                for (int r5 = 0; r5 < 4; ++r5)                                         \
                    p += w2r[tf][r5] * fmaxf(accf[tf][r5], 0.0f);                      \
            p += __shfl_xor(p, 16);                                                    \
            p += __shfl_xor(p, 32);                                                    \
            float d = p + bf2;                                                         \
            if (wv == 0 && lane < 16)                                                  \
                out[(size_t)(b0 + lane) * TSTEPS + ((T) - 1)] = d;                     \
            hsplit(d, &dh, &dl);                                                       \
        }                                                                              \
        /* P1b: x/delta/bias contribution (kt=0), last in the acc chain */             \
        {                                                                              \
            half8 bh0, bl0;                                                            \
            if (quad < 2) {                                                            \
                bh0 = *(const half8*)(&Xh[CUR][col * RS + k0q]);                       \
                bl0 = *(const half8*)(&Xl[CUR][col * RS + k0q]);                       \
            } else {                                                                   \
                bh0 = hz; bl0 = hz;                                                    \
                if (quad == 2) { bh0[0] = dh; bh0[1] = (half_t)1.0f; bl0[0] = dl; }    \
            }                                                                          \
            _Pragma("unroll")                                                          \
            for (int ti = 0; ti < 2; ++ti)                                             \
                if (ti < tcnt) {                                                       \
                    acc[ti] = MFMA16(a0f[0][ti], bh0, acc[ti]);                        \
                    acc[ti] = MFMA16(a0f[0][ti], bl0, acc[ti]);                        \
                }                                                                      \
        }                                                                              \
        /* P2: layer-0 cell update -> h0(T) into NXT */                                \
        _Pragma("unroll")                                                              \
        for (int ti = 0; ti < 2; ++ti)                                                 \
            if (ti < tcnt) {                                                           \
                int u = 8 * wv + 4 * ti + quad;                                        \
                float i_ = sig_u(acc[ti][0]);                                          \
                float f_ = sig_u(acc[ti][1]);                                          \
                float g_ = tanh_u(acc[ti][2]);                                         \
                float o_ = sig_u(acc[ti][3]);                                          \
                float c  = f_ * c0s[ti] + i_ * g_;                                     \
                c0s[ti]  = c;                                                          \
                float hv = o_ * tanh_c(c);                                             \
                if (u < HID) {                                                         \
                    half_t hh, hl; hsplit(hv, &hh, &hl);                               \
                    Xh[NXT][col * RS + OFF_H0 + u] = hh;                               \
                    Xl[NXT][col * RS + OFF_H0 + u] = hl;                               \
                }                                                                      \
            }                                                                          \
        __syncthreads();   /* B_a: h0(T) visible */                                    \
        /* feature staging for T+1 into NXT (x region; disjoint from reads below) */   \
        if (stager && ((T) + 1 < TSTEPS))                                              \
            hsplit(fnext, &Xh[NXT][xs * RS + xk], &Xl[NXT][xs * RS + xk]);             \
        /* P3: layer-1 gates: kt0,1 = h0(T) (NXT), kt2,3 = h1(T-1) (CUR) */            \
        floatx4 acc1[2]; acc1[0] = fz; acc1[1] = fz;                                   \
        _Pragma("unroll")                                                              \
        for (int kt = 0; kt < 2; ++kt) {                                               \
            half8 bh = *(const half8*)(&Xh[NXT][col * RS + OFF_H0 + 32 * kt + k0q]);   \
            half8 bl = *(const half8*)(&Xl[NXT][col * RS + OFF_H0 + 32 * kt + k0q]);   \
            _Pragma("unroll")                                                          \
            for (int ti = 0; ti < 2; ++ti)                                             \
                if (ti < tcnt) {                                                       \
                    acc1[ti] = MFMA16(a1f[kt][ti], bh, acc1[ti]);                      \
                    acc1[ti] = MFMA16(a1f[kt][ti], bl, acc1[ti]);                      \
                }                                                                      \
        }                                                                              \
        _Pragma("unroll")                                                              \
        for (int kt = 2; kt < 4; ++kt) {                                               \
            half8 bh = *(const half8*)(&Xh[CUR][col * RS + OFF_H1 + 32 * (kt - 2) + k0q]); \
            half8 bl = *(const half8*)(&Xl[CUR][col * RS + OFF_H1 + 32 * (kt - 2) + k0q]); \
            _Pragma("unroll")                                                          \
            for (int ti = 0; ti < 2; ++ti)                                             \
                if (ti < tcnt) {                                                       \
                    acc1[ti] = MFMA16(a1f[kt][ti], bh, acc1[ti]);                      \
                    acc1[ti] = MFMA16(a1f[kt][ti], bl, acc1[ti]);                      \
                }                                                                      \
        }                                                                              \
        /* P4: layer-1 cell update -> h1(T) into NXT */                                \
        _Pragma("unroll")                                                              \
        for (int ti = 0; ti < 2; ++ti)                                                 \
            if (ti < tcnt) {                                                           \
                int u = 8 * wv + 4 * ti + quad;                                        \
                float i_ = sig_u(acc1[ti][0]);                                         \
                float f_ = sig_u(acc1[ti][1]);                                         \
                float g_ = tanh_u(acc1[ti][2]);                                        \
                float o_ = sig_u(acc1[ti][3]);                                         \
                float c  = f_ * c1s[ti] + i_ * g_;                                     \
                c1s[ti]  = c;                                                          \
                float hv = o_ * tanh_c(c);                                             \
                if (u < HID) {                                                         \
                    half_t hh, hl; hsplit(hv, &hh, &hl);                               \
                    Xh[NXT][col * RS + OFF_H1 + u] = hh;                               \
                    Xl[NXT][col * RS + OFF_H1 + u] = hl;                               \
                }                                                                      \
            }                                                                          \
        __syncthreads();   /* B_b: h1(T) + features(T+1) visible */                    \
        /* P5-MFMA: FC accumulation for step T (reduce deferred to next step) */       \
        accf[0] = fz; accf[1] = fz;                                                    \
        _Pragma("unroll")                                                              \
        for (int kt = 0; kt < 2; ++kt) {                                               \
            half8 bh = *(const half8*)(&Xh[NXT][col * RS + OFF_H1 + 32 * kt + k0q]);   \
            half8 bl = *(const half8*)(&Xl[NXT][col * RS + OFF_H1 + 32 * kt + k0q]);   \
            _Pragma("unroll")                                                          \
            for (int tf = 0; tf < 2; ++tf) {                                           \
                accf[tf] = MFMA16(wff[kt][tf], bh, accf[tf]);                          \
                accf[tf] = MFMA16(wff[kt][tf], bl, accf[tf]);                          \
            }                                                                          \
        }                                                                              \
    }

    #pragma unroll 1
    for (int t = 0; t < TSTEPS; t += 2) {
        LSTM_STEP(t,     0, 1)
        LSTM_STEP(t + 1, 1, 0)
    }
#undef LSTM_STEP

    // ===== epilogue: reduce step-127 FC accumulator and write the last output =====
    {
        float p = 0.0f;
        #pragma unroll
        for (int tf = 0; tf < 2; ++tf)
            #pragma unroll
            for (int r5 = 0; r5 < 4; ++r5)
                p += w2r[tf][r5] * fmaxf(accf[tf][r5], 0.0f);
        p += __shfl_xor(p, 16);
        p += __shfl_xor(p, 32);
        if (wv == 0 && lane < 16)
            out[(size_t)(b0 + lane) * TSTEPS + (TSTEPS - 1)] = p + bf2;
    }
}

extern "C" void kernel_launch(void* const* d_in, const int* in_sizes, int n_in,
                              void* d_out, int out_size, void* d_ws, size_t ws_size,
                              hipStream_t stream) {
    const float* feat  = (const float*)d_in[0];
    const float* w_ih0 = (const float*)d_in[1];
    const float* w_hh0 = (const float*)d_in[2];
    const float* b_0   = (const float*)d_in[3];
    const float* w_ih1 = (const float*)d_in[4];
    const float* w_hh1 = (const float*)d_in[5];
    const float* b_1   = (const float*)d_in[6];
    const float* w_fc1 = (const float*)d_in[7];
    const float* b_fc1 = (const float*)d_in[8];
    const float* w_fc2 = (const float*)d_in[9];
    const float* b_fc2 = (const float*)d_in[10];
    float* out = (float*)d_out;

    dim3 grid(BATCH / BT);   // 512 blocks x 448 threads; ~38 KB LDS
    dim3 block(NTHREADS);
    hipLaunchKernelGGL(lstm2_w8_kernel, grid, block, 0, stream,
                       feat, w_ih0, w_hh0, b_0, w_ih1, w_hh1, b_1,
                       w_fc1, b_fc1, w_fc2, b_fc2, out);
}

// Round 9
// 446.485 us; speedup vs baseline: 1.0632x; 1.0632x over previous
//
#include <hip/hip_runtime.h>
#include <math.h>

#define BATCH    8192
#define TSTEPS   128
#define SDIM     16
#define HID      50
#define IN0      17
#define BT       16     // samples per block = MFMA N
#define NTHREADS 448    // 7 waves

// X row layout (f16 elems), double-buffered, stride RS:
//  k 0..15: features   k16: delta (reg-injected)  k17: one (reg-injected, bias col)
//  k18..31: zero       k32..95: h0 (u0..49 real, u50=const-1 for b_1, rest 0)
//  k96..159: h1 (u0..49 real, u50=const-1 for b_fc1, rest 0)
// RS=168: 84 dwords == 20 (mod 32) -> b128 reads spread over 8 bank-groups (2-way, free).
// REGISTER BUDGET (R2/R4/R5/R8 lessons): hard cap 128 unified VGPR (launch_bounds 448,4).
// R3 live set ~111. Spilled: +40 bias regs (R2), +32 carried frags (R4), +16 phase-local
// accs (R5), and even the UNROLLx2 body (R8: duplicated live ranges, WRITE 5.9->13MB,
// -8%). NO register increases AND no body doubling. Tripwires: FETCH>40MB / WRITE>10MB.
// R5-kept: log2(e) folded into staged gate weights -> native exp2 activations (0 regs).
// R9: buffer swap via ONE wave-uniform XOR offset (xc ^= BT*RS) instead of 4 swapped
//     pointers -> ds-immediate folding like R8's unroll, at R6's body size. Reg-negative.
#define RS      168
#define XSZ     (BT * RS)    // 2688 halves per buffer; xc toggles 0 <-> XSZ
#define OFF_H0  32
#define OFF_H1  96
#define W0K     96      // cols: [w_ih0(17) | b_0(@17) | 0..31 | w_hh0(50)+0pad]
#define W1K     128     // cols: [w_ih1(50) | b_1(@50) | 0..63 | w_hh1(50) | 0(@50!) +pad]
#define WFK     64      // cols: [w_fc1(50) | b_fc1(@50) | 0 pad]   (FC NOT pre-scaled!)

#define LOG2E_F  1.44269504088896f

typedef _Float16 half_t;
typedef __attribute__((ext_vector_type(8))) _Float16 half8;
typedef __attribute__((ext_vector_type(4))) float    floatx4;

#define MFMA16(a, b, c) __builtin_amdgcn_mfma_f32_16x16x32_f16((a), (b), (c), 0, 0, 0)

// Gate pre-activations arrive PRE-SCALED by log2(e) (folded into staged weights),
// so sigmoid/tanh use native exp2 with no scale mul.
__device__ __forceinline__ float sig_u(float y) {    // y = x*log2e
    return __builtin_amdgcn_rcpf(1.0f + __builtin_amdgcn_exp2f(-y));
}
__device__ __forceinline__ float tanh_u(float y) {   // y = x*log2e
    return fmaf(2.0f, __builtin_amdgcn_rcpf(1.0f + __builtin_amdgcn_exp2f(-2.0f * y)), -1.0f);
}
__device__ __forceinline__ float tanh_c(float c) {   // c in normal domain (cell state)
    return fmaf(2.0f, __builtin_amdgcn_rcpf(1.0f + __builtin_amdgcn_exp2f(c * (-2.0f * LOG2E_F))), -1.0f);
}
__device__ __forceinline__ void hsplit(float v, half_t* hp, half_t* lp) {
    half_t h = (half_t)v;
    *hp = h;
    *lp = (half_t)(v - (float)h);
}

__global__ __launch_bounds__(NTHREADS, 4)   // VGPR cap 128 (unified)
void lstm2_w8_kernel(const float* __restrict__ feat,
                     const float* __restrict__ w_ih0,
                     const float* __restrict__ w_hh0,
                     const float* __restrict__ b_0,
                     const float* __restrict__ w_ih1,
                     const float* __restrict__ w_hh1,
                     const float* __restrict__ b_1,
                     const float* __restrict__ w_fc1,
                     const float* __restrict__ b_fc1,
                     const float* __restrict__ w_fc2,
                     const float* __restrict__ b_fc2,
                     float* __restrict__ out)
{
    __shared__ __align__(16) half_t smW[64 * W1K];               // 16 KB chunk scratch
    __shared__ __align__(16) half_t XhB[2 * XSZ];                // 10.5 KB (both buffers)
    __shared__ __align__(16) half_t XlB[2 * XSZ];                // 10.5 KB  (~38 KB total)

    const int tid  = threadIdx.x;
    const int lane = tid & 63;
    const int wv   = tid >> 6;          // 0..6; wave w owns M-tiles {2w, 2w+1} (13 real tiles)
    const int quad = lane >> 4;
    const int col  = lane & 15;
    const int k0q  = quad * 8;
    const int b0   = blockIdx.x * BT;
    const int tcnt = (wv < 6) ? 2 : 1;  // wave 6 owns 1 real tile (rows 192..207); rows>=200 zero

    // Unit-interleaved rows: row 4j+q = gate q (i,f,g,o) of unit j; orig = q*50+j. Rows>=200 zero.
    auto w0val = [&](int r, int k) -> float {
        if (r >= 200) return 0.0f;
        int j = r >> 2, q = r & 3, orig = q * HID + j;
        if (k < IN0)  return w_ih0[orig * IN0 + k];
        if (k == IN0) return b_0[orig];                       // bias via x const-1 @k17
        if (k < OFF_H0) return 0.0f;
        int u = k - OFF_H0;
        return (u < HID) ? w_hh0[orig * HID + u] : 0.0f;      // h0-pad cols (incl u50) zero
    };
    auto w1val = [&](int r, int k) -> float {
        if (r >= 200) return 0.0f;
        int j = r >> 2, q = r & 3, orig = q * HID + j;
        if (k < 64) {
            if (k < HID)  return w_ih1[orig * HID + k];       // x h0
            if (k == HID) return b_1[orig];                   // bias via h0 const-1 slot
            return 0.0f;
        }
        int u = k - 64;                                       // x h1; u50 stays 0 (protects FC const-1)
        return (u < HID) ? w_hh1[orig * HID + u] : 0.0f;
    };

    // ---- stage weights through 16KB scratch, 64-row chunks; waves {2c,2c+1} grab frags of chunk c
    //      Gate weights (incl bias + delta cols) pre-scaled by log2(e) for exp2 activations.
    half8 a0f[3][2], a1f[4][2];
    const int lbase = 32 * (wv & 1) + col;
    #pragma unroll 1
    for (int c = 0; c < 4; ++c) {
        for (int i = tid; i < 64 * W0K; i += NTHREADS) {
            int r = i / W0K, k = i - r * W0K;
            smW[i] = (half_t)(w0val(64 * c + r, k) * LOG2E_F);
        }
        __syncthreads();
        if ((wv >> 1) == c) {
            #pragma unroll
            for (int kt = 0; kt < 3; ++kt)
                #pragma unroll
                for (int ti = 0; ti < 2; ++ti)
                    a0f[kt][ti] = *(const half8*)(smW + (lbase + 16 * ti) * W0K + 32 * kt + k0q);
        }
        __syncthreads();
    }
    #pragma unroll 1
    for (int c = 0; c < 4; ++c) {
        for (int i = tid; i < 64 * W1K; i += NTHREADS) {
            int r = i >> 7, k = i & 127;
            smW[i] = (half_t)(w1val(64 * c + r, k) * LOG2E_F);
        }
        __syncthreads();
        if ((wv >> 1) == c) {
            #pragma unroll
            for (int kt = 0; kt < 4; ++kt)
                #pragma unroll
                for (int ti = 0; ti < 2; ++ti)
                    a1f[kt][ti] = *(const half8*)(smW + (lbase + 16 * ti) * W1K + 32 * kt + k0q);
        }
        __syncthreads();
    }
    // Wf (32x64): rows 0..24 real, col 50 = b_fc1. NOT scaled (linear/ReLU path).
    for (int i = tid; i < 32 * WFK; i += NTHREADS) {
        int r = i >> 6, k = i & 63;
        float v = 0.0f;
        if (r < 25) { if (k < HID) v = w_fc1[r * HID + k]; else if (k == HID) v = b_fc1[r]; }
        smW[i] = (half_t)v;
    }
    __syncthreads();
    half8 wff[2][2];
    #pragma unroll
    for (int kt = 0; kt < 2; ++kt)
        #pragma unroll
        for (int tf = 0; tf < 2; ++tf)
            wff[kt][tf] = *(const half8*)(smW + (16 * tf + col) * WFK + 32 * kt + k0q);

    // ---- X buffers: zero, then const-1 slots + t=0 features (barrier between)
    for (int i = tid; i < 2 * XSZ; i += NTHREADS) {
        XhB[i] = (half_t)0.0f; XlB[i] = (half_t)0.0f;
    }
    __syncthreads();
    if (tid < BT) {   // const-1 slots (hi=1, lo=0) in BOTH buffers; never overwritten (u<50 store guard)
        XhB[tid * RS + OFF_H0 + HID]       = (half_t)1.0f;
        XhB[XSZ + tid * RS + OFF_H0 + HID] = (half_t)1.0f;
        XhB[tid * RS + OFF_H1 + HID]       = (half_t)1.0f;
        XhB[XSZ + tid * RS + OFF_H1 + HID] = (half_t)1.0f;
    }
    const bool stager = (tid < BT * SDIM);                // 256 feature loaders (waves 0-3)
    const int  xs = tid >> 4, xk = tid & 15;
    const size_t fbase = (size_t)(b0 + (stager ? xs : 0)) * (TSTEPS * SDIM) + xk;
    if (stager) hsplit(feat[fbase], &XhB[xs * RS + xk], &XlB[xs * RS + xk]);

    // ---- per-lane FC output consts (all waves: FC is computed redundantly everywhere)
    floatx4 w2r[2];
    { floatx4 z = {0.f, 0.f, 0.f, 0.f}; w2r[0] = z; w2r[1] = z; }
    #pragma unroll
    for (int tf = 0; tf < 2; ++tf)
        #pragma unroll
        for (int r5 = 0; r5 < 4; ++r5) {
            int r = 16 * tf + 4 * quad + r5;
            if (r < 25) w2r[tf][r5] = w_fc2[r];
        }
    const float bf2 = b_fc2[0];

    const half8   hz = {0, 0, 0, 0, 0, 0, 0, 0};
    const floatx4 fz = {0.f, 0.f, 0.f, 0.f};
    float c0s[2] = {0.f, 0.f};
    float c1s[2] = {0.f, 0.f};
    half_t dh = (half_t)0.0f, dl = (half_t)0.0f;   // prev_delta hi/lo (reg-resident)
    floatx4 accf[2]; accf[0] = fz; accf[1] = fz;   // FC accumulator, carried across loop edge

    int xc = 0;                                    // CUR buffer offset; toggles 0 <-> XSZ
    __syncthreads();

    #pragma unroll 1
    for (int t = 0; t < TSTEPS; ++t) {
        const int xn = xc ^ XSZ;                   // NXT buffer offset (transient)
        float fnext = 0.0f;
        if (stager && (t + 1 < TSTEPS)) fnext = feat[fbase + (size_t)(t + 1) * SDIM];

        // ===== P1a: layer-0 gates, h0 contribution (kt=1,2) — independent of prev delta.
        floatx4 acc[2]; acc[0] = fz; acc[1] = fz;
        #pragma unroll
        for (int kt = 1; kt < 3; ++kt) {
            half8 bh = *(const half8*)(&XhB[xc + col * RS + OFF_H0 + 32 * (kt - 1) + k0q]);
            half8 bl = *(const half8*)(&XlB[xc + col * RS + OFF_H0 + 32 * (kt - 1) + k0q]);
            #pragma unroll
            for (int ti = 0; ti < 2; ++ti)
                if (ti < tcnt) {
                    acc[ti] = MFMA16(a0f[kt][ti], bh, acc[ti]);
                    acc[ti] = MFMA16(a0f[kt][ti], bl, acc[ti]);
                }
        }

        // ===== deferred FC reduce of step t-1 (rotated across the loop edge) =====
        if (t) {
            float p = 0.0f;
            #pragma unroll
            for (int tf = 0; tf < 2; ++tf)
                #pragma unroll
                for (int r5 = 0; r5 < 4; ++r5)
                    p += w2r[tf][r5] * fmaxf(accf[tf][r5], 0.0f);
            p += __shfl_xor(p, 16);
            p += __shfl_xor(p, 32);          // every lane holds d for its col
            float d = p + bf2;
            if (wv == 0 && lane < 16)
                out[(size_t)(b0 + lane) * TSTEPS + (t - 1)] = d;
            hsplit(d, &dh, &dl);             // reg-resident prev_delta
        }

        // ===== P1b: x/delta/bias contribution (kt=0), last in the acc chain =====
        {
            half8 bh0, bl0;
            if (quad < 2) {
                bh0 = *(const half8*)(&XhB[xc + col * RS + k0q]);
                bl0 = *(const half8*)(&XlB[xc + col * RS + k0q]);
            } else {
                bh0 = hz; bl0 = hz;
                if (quad == 2) { bh0[0] = dh; bh0[1] = (half_t)1.0f; bl0[0] = dl; }
            }
            #pragma unroll
            for (int ti = 0; ti < 2; ++ti)
                if (ti < tcnt) {
                    acc[ti] = MFMA16(a0f[0][ti], bh0, acc[ti]);
                    acc[ti] = MFMA16(a0f[0][ti], bl0, acc[ti]);
                }
        }

        // ===== P2: layer-0 cell update -> h0(t) into NXT =====
        #pragma unroll
        for (int ti = 0; ti < 2; ++ti)
            if (ti < tcnt) {
                int u = 8 * wv + 4 * ti + quad;
                float i_ = sig_u(acc[ti][0]);
                float f_ = sig_u(acc[ti][1]);
                float g_ = tanh_u(acc[ti][2]);
                float o_ = sig_u(acc[ti][3]);
                float c  = f_ * c0s[ti] + i_ * g_;
                c0s[ti]  = c;
                float hv = o_ * tanh_c(c);
                if (u < HID) {
                    half_t hh, hl; hsplit(hv, &hh, &hl);
                    XhB[xn + col * RS + OFF_H0 + u] = hh;
                    XlB[xn + col * RS + OFF_H0 + u] = hl;
                }
            }
        __syncthreads();   // B_a: h0(t) visible

        // feature staging for t+1 into NXT (x region; disjoint from all reads below)
        if (stager && (t + 1 < TSTEPS))
            hsplit(fnext, &XhB[xn + xs * RS + xk], &XlB[xn + xs * RS + xk]);

        // ===== P3: layer-1 gates: kt0,1 = h0(t) (NXT), kt2,3 = h1(t-1) (CUR) =====
        floatx4 acc1[2]; acc1[0] = fz; acc1[1] = fz;
        #pragma unroll
        for (int kt = 0; kt < 2; ++kt) {
            half8 bh = *(const half8*)(&XhB[xn + col * RS + OFF_H0 + 32 * kt + k0q]);
            half8 bl = *(const half8*)(&XlB[xn + col * RS + OFF_H0 + 32 * kt + k0q]);
            #pragma unroll
            for (int ti = 0; ti < 2; ++ti)
                if (ti < tcnt) {
                    acc1[ti] = MFMA16(a1f[kt][ti], bh, acc1[ti]);
                    acc1[ti] = MFMA16(a1f[kt][ti], bl, acc1[ti]);
                }
        }
        #pragma unroll
        for (int kt = 2; kt < 4; ++kt) {
            half8 bh = *(const half8*)(&XhB[xc + col * RS + OFF_H1 + 32 * (kt - 2) + k0q]);
            half8 bl = *(const half8*)(&XlB[xc + col * RS + OFF_H1 + 32 * (kt - 2) + k0q]);
            #pragma unroll
            for (int ti = 0; ti < 2; ++ti)
                if (ti < tcnt) {
                    acc1[ti] = MFMA16(a1f[kt][ti], bh, acc1[ti]);
                    acc1[ti] = MFMA16(a1f[kt][ti], bl, acc1[ti]);
                }
        }

        // ===== P4: layer-1 cell update -> h1(t) into NXT =====
        #pragma unroll
        for (int ti = 0; ti < 2; ++ti)
            if (ti < tcnt) {
                int u = 8 * wv + 4 * ti + quad;
                float i_ = sig_u(acc1[ti][0]);
                float f_ = sig_u(acc1[ti][1]);
                float g_ = tanh_u(acc1[ti][2]);
                float o_ = sig_u(acc1[ti][3]);
                float c  = f_ * c1s[ti] + i_ * g_;
                c1s[ti]  = c;
                float hv = o_ * tanh_c(c);
                if (u < HID) {
                    half_t hh, hl; hsplit(hv, &hh, &hl);
                    XhB[xn + col * RS + OFF_H1 + u] = hh;
                    XlB[xn + col * RS + OFF_H1 + u] = hl;
                }
            }
        __syncthreads();   // B_b: h1(t) + features(t+1) visible

        // ===== P5-MFMA: FC accumulation for step t (reduce deferred to next iteration).
        //       Redundant on all waves (each wave needs d). b_fc1 via const-1 col 50.
        accf[0] = fz; accf[1] = fz;
        #pragma unroll
        for (int kt = 0; kt < 2; ++kt) {
            half8 bh = *(const half8*)(&XhB[xn + col * RS + OFF_H1 + 32 * kt + k0q]);
            half8 bl = *(const half8*)(&XlB[xn + col * RS + OFF_H1 + 32 * kt + k0q]);
            #pragma unroll
            for (int tf = 0; tf < 2; ++tf) {
                accf[tf] = MFMA16(wff[kt][tf], bh, accf[tf]);
                accf[tf] = MFMA16(wff[kt][tf], bl, accf[tf]);
            }
        }

        xc = xn;   // swap buffers (no barrier needed: next P1/P2 touch only regions
                   // whose last cross-wave access is already separated by B_a/B_b)
    }

    // ===== epilogue: reduce step-127 FC accumulator and write the last output =====
    {
        float p = 0.0f;
        #pragma unroll
        for (int tf = 0; tf < 2; ++tf)
            #pragma unroll
            for (int r5 = 0; r5 < 4; ++r5)
                p += w2r[tf][r5] * fmaxf(accf[tf][r5], 0.0f);
        p += __shfl_xor(p, 16);
        p += __shfl_xor(p, 32);
        if (wv == 0 && lane < 16)
            out[(size_t)(b0 + lane) * TSTEPS + (TSTEPS - 1)] = p + bf2;
    }
}

extern "C" void kernel_launch(void* const* d_in, const int* in_sizes, int n_in,
                              void* d_out, int out_size, void* d_ws, size_t ws_size,
                              hipStream_t stream) {
    const float* feat  = (const float*)d_in[0];
    const float* w_ih0 = (const float*)d_in[1];
    const float* w_hh0 = (const float*)d_in[2];
    const float* b_0   = (const float*)d_in[3];
    const float* w_ih1 = (const float*)d_in[4];
    const float* w_hh1 = (const float*)d_in[5];
    const float* b_1   = (const float*)d_in[6];
    const float* w_fc1 = (const float*)d_in[7];
    const float* b_fc1 = (const float*)d_in[8];
    const float* w_fc2 = (const float*)d_in[9];
    const float* b_fc2 = (const float*)d_in[10];
    float* out = (float*)d_out;

    dim3 grid(BATCH / BT);   // 512 blocks x 448 threads; ~38 KB LDS
    dim3 block(NTHREADS);
    hipLaunchKernelGGL(lstm2_w8_kernel, grid, block, 0, stream,
                       feat, w_ih0, w_hh0, b_0, w_ih1, w_hh1, b_1,
                       w_fc1, b_fc1, w_fc2, b_fc2, out);
}

// Round 10
// 423.563 us; speedup vs baseline: 1.1208x; 1.0541x over previous
//
#include <hip/hip_runtime.h>
#include <math.h>

#define BATCH    8192
#define TSTEPS   128
#define SDIM     16
#define HID      50
#define IN0      17
#define BT       16     // samples per block = MFMA N
#define NTHREADS 448    // 7 waves

// X row layout (f16 elems), double-buffered, stride RS:
//  k 0..15: features   k16: delta (reg-injected)  k17: one (reg-injected, bias col)
//  k18..31: zero       k32..95: h0 (u0..49 real, u50=const-1 for b_1, rest 0)
//  k96..159: h1 (u0..49 real, u50=const-1 for b_fc1, rest 0)
// RS=168: 84 dwords == 20 (mod 32) -> b128 reads spread over 8 bank-groups (2-way, free).
// REGISTER BUDGET (R2/R4/R5/R8): hard cap 128 unified VGPR (launch_bounds 448,4).
// Live set ~111. Spilled: +40 bias regs (R2), +32 carried frags (R4), +16 phase-local
// accs (R5), unrollx2 body (R8). NO register increases, no body doubling.
// Tripwires: FETCH>40MB / WRITE>10MB = spill.
// R5-kept: log2(e) folded into staged gate weights -> native exp2 activations.
// R9-kept: buffer swap via one wave-uniform XOR offset (xc ^= XSZ) -> ds-imm folding.
// R10: 14 uniform tiles (wave 6 tile 2 = zero-weight dummy; stores guarded u<HID) ->
//      no tcnt guards, straight-line MFMA runs on all waves; P1b branchless
//      (unconditional LDS read of zero region + element overlay for delta/one).
#define RS      168
#define XSZ     (BT * RS)    // 2688 halves per buffer; xc toggles 0 <-> XSZ
#define OFF_H0  32
#define OFF_H1  96
#define W0K     96      // cols: [w_ih0(17) | b_0(@17) | 0..31 | w_hh0(50)+0pad]
#define W1K     128     // cols: [w_ih1(50) | b_1(@50) | 0..63 | w_hh1(50) | 0(@50!) +pad]
#define WFK     64      // cols: [w_fc1(50) | b_fc1(@50) | 0 pad]   (FC NOT pre-scaled!)

#define LOG2E_F  1.44269504088896f

typedef _Float16 half_t;
typedef __attribute__((ext_vector_type(8))) _Float16 half8;
typedef __attribute__((ext_vector_type(4))) float    floatx4;

#define MFMA16(a, b, c) __builtin_amdgcn_mfma_f32_16x16x32_f16((a), (b), (c), 0, 0, 0)

// Gate pre-activations arrive PRE-SCALED by log2(e) (folded into staged weights),
// so sigmoid/tanh use native exp2 with no scale mul.
__device__ __forceinline__ float sig_u(float y) {    // y = x*log2e
    return __builtin_amdgcn_rcpf(1.0f + __builtin_amdgcn_exp2f(-y));
}
__device__ __forceinline__ float tanh_u(float y) {   // y = x*log2e
    return fmaf(2.0f, __builtin_amdgcn_rcpf(1.0f + __builtin_amdgcn_exp2f(-2.0f * y)), -1.0f);
}
__device__ __forceinline__ float tanh_c(float c) {   // c in normal domain (cell state)
    return fmaf(2.0f, __builtin_amdgcn_rcpf(1.0f + __builtin_amdgcn_exp2f(c * (-2.0f * LOG2E_F))), -1.0f);
}
__device__ __forceinline__ void hsplit(float v, half_t* hp, half_t* lp) {
    half_t h = (half_t)v;
    *hp = h;
    *lp = (half_t)(v - (float)h);
}

__global__ __launch_bounds__(NTHREADS, 4)   // VGPR cap 128 (unified)
void lstm2_w8_kernel(const float* __restrict__ feat,
                     const float* __restrict__ w_ih0,
                     const float* __restrict__ w_hh0,
                     const float* __restrict__ b_0,
                     const float* __restrict__ w_ih1,
                     const float* __restrict__ w_hh1,
                     const float* __restrict__ b_1,
                     const float* __restrict__ w_fc1,
                     const float* __restrict__ b_fc1,
                     const float* __restrict__ w_fc2,
                     const float* __restrict__ b_fc2,
                     float* __restrict__ out)
{
    __shared__ __align__(16) half_t smW[64 * W1K];               // 16 KB chunk scratch
    __shared__ __align__(16) half_t XhB[2 * XSZ];                // 10.5 KB (both buffers)
    __shared__ __align__(16) half_t XlB[2 * XSZ];                // 10.5 KB  (~38 KB total)

    const int tid  = threadIdx.x;
    const int lane = tid & 63;
    const int wv   = tid >> 6;          // 0..6; wave w owns M-tiles {2w, 2w+1} (14 tiles, 13 real)
    const int quad = lane >> 4;
    const int col  = lane & 15;
    const int k0q  = quad * 8;
    const int b0   = blockIdx.x * BT;

    // Unit-interleaved rows: row 4j+q = gate q (i,f,g,o) of unit j; orig = q*50+j. Rows>=200 zero.
    auto w0val = [&](int r, int k) -> float {
        if (r >= 200) return 0.0f;
        int j = r >> 2, q = r & 3, orig = q * HID + j;
        if (k < IN0)  return w_ih0[orig * IN0 + k];
        if (k == IN0) return b_0[orig];                       // bias via x const-1 @k17
        if (k < OFF_H0) return 0.0f;
        int u = k - OFF_H0;
        return (u < HID) ? w_hh0[orig * HID + u] : 0.0f;      // h0-pad cols (incl u50) zero
    };
    auto w1val = [&](int r, int k) -> float {
        if (r >= 200) return 0.0f;
        int j = r >> 2, q = r & 3, orig = q * HID + j;
        if (k < 64) {
            if (k < HID)  return w_ih1[orig * HID + k];       // x h0
            if (k == HID) return b_1[orig];                   // bias via h0 const-1 slot
            return 0.0f;
        }
        int u = k - 64;                                       // x h1; u50 stays 0 (protects FC const-1)
        return (u < HID) ? w_hh1[orig * HID + u] : 0.0f;
    };

    // ---- stage weights through 16KB scratch, 64-row chunks; waves {2c,2c+1} grab frags of chunk c
    //      Gate weights (incl bias + delta cols) pre-scaled by log2(e) for exp2 activations.
    half8 a0f[3][2], a1f[4][2];
    const int lbase = 32 * (wv & 1) + col;
    #pragma unroll 1
    for (int c = 0; c < 4; ++c) {
        for (int i = tid; i < 64 * W0K; i += NTHREADS) {
            int r = i / W0K, k = i - r * W0K;
            smW[i] = (half_t)(w0val(64 * c + r, k) * LOG2E_F);
        }
        __syncthreads();
        if ((wv >> 1) == c) {
            #pragma unroll
            for (int kt = 0; kt < 3; ++kt)
                #pragma unroll
                for (int ti = 0; ti < 2; ++ti)
                    a0f[kt][ti] = *(const half8*)(smW + (lbase + 16 * ti) * W0K + 32 * kt + k0q);
        }
        __syncthreads();
    }
    #pragma unroll 1
    for (int c = 0; c < 4; ++c) {
        for (int i = tid; i < 64 * W1K; i += NTHREADS) {
            int r = i >> 7, k = i & 127;
            smW[i] = (half_t)(w1val(64 * c + r, k) * LOG2E_F);
        }
        __syncthreads();
        if ((wv >> 1) == c) {
            #pragma unroll
            for (int kt = 0; kt < 4; ++kt)
                #pragma unroll
                for (int ti = 0; ti < 2; ++ti)
                    a1f[kt][ti] = *(const half8*)(smW + (lbase + 16 * ti) * W1K + 32 * kt + k0q);
        }
        __syncthreads();
    }
    // Wf (32x64): rows 0..24 real, col 50 = b_fc1. NOT scaled (linear/ReLU path).
    for (int i = tid; i < 32 * WFK; i += NTHREADS) {
        int r = i >> 6, k = i & 63;
        float v = 0.0f;
        if (r < 25) { if (k < HID) v = w_fc1[r * HID + k]; else if (k == HID) v = b_fc1[r]; }
        smW[i] = (half_t)v;
    }
    __syncthreads();
    half8 wff[2][2];
    #pragma unroll
    for (int kt = 0; kt < 2; ++kt)
        #pragma unroll
        for (int tf = 0; tf < 2; ++tf)
            wff[kt][tf] = *(const half8*)(smW + (16 * tf + col) * WFK + 32 * kt + k0q);

    // ---- X buffers: zero, then const-1 slots + t=0 features (barrier between)
    for (int i = tid; i < 2 * XSZ; i += NTHREADS) {
        XhB[i] = (half_t)0.0f; XlB[i] = (half_t)0.0f;
    }
    __syncthreads();
    if (tid < BT) {   // const-1 slots (hi=1, lo=0) in BOTH buffers; never overwritten (u<50 store guard)
        XhB[tid * RS + OFF_H0 + HID]       = (half_t)1.0f;
        XhB[XSZ + tid * RS + OFF_H0 + HID] = (half_t)1.0f;
        XhB[tid * RS + OFF_H1 + HID]       = (half_t)1.0f;
        XhB[XSZ + tid * RS + OFF_H1 + HID] = (half_t)1.0f;
    }
    const bool stager = (tid < BT * SDIM);                // 256 feature loaders (waves 0-3)
    const int  xs = tid >> 4, xk = tid & 15;
    const size_t fbase = (size_t)(b0 + (stager ? xs : 0)) * (TSTEPS * SDIM) + xk;
    if (stager) hsplit(feat[fbase], &XhB[xs * RS + xk], &XlB[xs * RS + xk]);

    // ---- per-lane FC output consts (all waves: FC is computed redundantly everywhere)
    floatx4 w2r[2];
    { floatx4 z = {0.f, 0.f, 0.f, 0.f}; w2r[0] = z; w2r[1] = z; }
    #pragma unroll
    for (int tf = 0; tf < 2; ++tf)
        #pragma unroll
        for (int r5 = 0; r5 < 4; ++r5) {
            int r = 16 * tf + 4 * quad + r5;
            if (r < 25) w2r[tf][r5] = w_fc2[r];
        }
    const float bf2 = b_fc2[0];

    const floatx4 fz = {0.f, 0.f, 0.f, 0.f};
    float c0s[2] = {0.f, 0.f};      // wave 6 ti=1: dummy (zero weights), never stored
    float c1s[2] = {0.f, 0.f};
    half_t dh = (half_t)0.0f, dl = (half_t)0.0f;   // prev_delta hi/lo (reg-resident)
    floatx4 accf[2]; accf[0] = fz; accf[1] = fz;   // FC accumulator, carried across loop edge

    int xc = 0;                                    // CUR buffer offset; toggles 0 <-> XSZ
    __syncthreads();

    #pragma unroll 1
    for (int t = 0; t < TSTEPS; ++t) {
        const int xn = xc ^ XSZ;                   // NXT buffer offset (transient)
        float fnext = 0.0f;
        if (stager && (t + 1 < TSTEPS)) fnext = feat[fbase + (size_t)(t + 1) * SDIM];

        // ===== P1a: layer-0 gates, h0 contribution (kt=1,2) — independent of prev delta.
        floatx4 acc[2]; acc[0] = fz; acc[1] = fz;
        #pragma unroll
        for (int kt = 1; kt < 3; ++kt) {
            half8 bh = *(const half8*)(&XhB[xc + col * RS + OFF_H0 + 32 * (kt - 1) + k0q]);
            half8 bl = *(const half8*)(&XlB[xc + col * RS + OFF_H0 + 32 * (kt - 1) + k0q]);
            #pragma unroll
            for (int ti = 0; ti < 2; ++ti) {
                acc[ti] = MFMA16(a0f[kt][ti], bh, acc[ti]);
                acc[ti] = MFMA16(a0f[kt][ti], bl, acc[ti]);
            }
        }

        // ===== deferred FC reduce of step t-1 (rotated across the loop edge) =====
        if (t) {
            float p = 0.0f;
            #pragma unroll
            for (int tf = 0; tf < 2; ++tf)
                #pragma unroll
                for (int r5 = 0; r5 < 4; ++r5)
                    p += w2r[tf][r5] * fmaxf(accf[tf][r5], 0.0f);
            p += __shfl_xor(p, 16);
            p += __shfl_xor(p, 32);          // every lane holds d for its col
            float d = p + bf2;
            if (wv == 0 && lane < 16)
                out[(size_t)(b0 + lane) * TSTEPS + (t - 1)] = d;
            hsplit(d, &dh, &dl);             // reg-resident prev_delta
        }

        // ===== P1b: x/delta/bias contribution (kt=0), last in the acc chain.
        //       Branchless: k16..31 of x region is ZERO in LDS, so read unconditionally
        //       (quads 2,3 get zeros) and overlay delta/one on quad 2 via element inserts.
        {
            half8 bh0 = *(const half8*)(&XhB[xc + col * RS + k0q]);
            half8 bl0 = *(const half8*)(&XlB[xc + col * RS + k0q]);
            if (quad == 2) { bh0[0] = dh; bh0[1] = (half_t)1.0f; bl0[0] = dl; }
            #pragma unroll
            for (int ti = 0; ti < 2; ++ti) {
                acc[ti] = MFMA16(a0f[0][ti], bh0, acc[ti]);
                acc[ti] = MFMA16(a0f[0][ti], bl0, acc[ti]);
            }
        }

        // ===== P2: layer-0 cell update -> h0(t) into NXT =====
        #pragma unroll
        for (int ti = 0; ti < 2; ++ti) {
            int u = 8 * wv + 4 * ti + quad;
            float i_ = sig_u(acc[ti][0]);
            float f_ = sig_u(acc[ti][1]);
            float g_ = tanh_u(acc[ti][2]);
            float o_ = sig_u(acc[ti][3]);
            float c  = f_ * c0s[ti] + i_ * g_;
            c0s[ti]  = c;
            float hv = o_ * tanh_c(c);
            if (u < HID) {
                half_t hh, hl; hsplit(hv, &hh, &hl);
                XhB[xn + col * RS + OFF_H0 + u] = hh;
                XlB[xn + col * RS + OFF_H0 + u] = hl;
            }
        }
        __syncthreads();   // B_a: h0(t) visible

        // feature staging for t+1 into NXT (x region; disjoint from all reads below)
        if (stager && (t + 1 < TSTEPS))
            hsplit(fnext, &XhB[xn + xs * RS + xk], &XlB[xn + xs * RS + xk]);

        // ===== P3: layer-1 gates: kt0,1 = h0(t) (NXT), kt2,3 = h1(t-1) (CUR) =====
        floatx4 acc1[2]; acc1[0] = fz; acc1[1] = fz;
        #pragma unroll
        for (int kt = 0; kt < 2; ++kt) {
            half8 bh = *(const half8*)(&XhB[xn + col * RS + OFF_H0 + 32 * kt + k0q]);
            half8 bl = *(const half8*)(&XlB[xn + col * RS + OFF_H0 + 32 * kt + k0q]);
            #pragma unroll
            for (int ti = 0; ti < 2; ++ti) {
                acc1[ti] = MFMA16(a1f[kt][ti], bh, acc1[ti]);
                acc1[ti] = MFMA16(a1f[kt][ti], bl, acc1[ti]);
            }
        }
        #pragma unroll
        for (int kt = 2; kt < 4; ++kt) {
            half8 bh = *(const half8*)(&XhB[xc + col * RS + OFF_H1 + 32 * (kt - 2) + k0q]);
            half8 bl = *(const half8*)(&XlB[xc + col * RS + OFF_H1 + 32 * (kt - 2) + k0q]);
            #pragma unroll
            for (int ti = 0; ti < 2; ++ti) {
                acc1[ti] = MFMA16(a1f[kt][ti], bh, acc1[ti]);
                acc1[ti] = MFMA16(a1f[kt][ti], bl, acc1[ti]);
            }
        }

        // ===== P4: layer-1 cell update -> h1(t) into NXT =====
        #pragma unroll
        for (int ti = 0; ti < 2; ++ti) {
            int u = 8 * wv + 4 * ti + quad;
            float i_ = sig_u(acc1[ti][0]);
            float f_ = sig_u(acc1[ti][1]);
            float g_ = tanh_u(acc1[ti][2]);
            float o_ = sig_u(acc1[ti][3]);
            float c  = f_ * c1s[ti] + i_ * g_;
            c1s[ti]  = c;
            float hv = o_ * tanh_c(c);
            if (u < HID) {
                half_t hh, hl; hsplit(hv, &hh, &hl);
                XhB[xn + col * RS + OFF_H1 + u] = hh;
                XlB[xn + col * RS + OFF_H1 + u] = hl;
            }
        }
        __syncthreads();   // B_b: h1(t) + features(t+1) visible

        // ===== P5-MFMA: FC accumulation for step t (reduce deferred to next iteration).
        //       Redundant on all waves (each wave needs d). b_fc1 via const-1 col 50.
        accf[0] = fz; accf[1] = fz;
        #pragma unroll
        for (int kt = 0; kt < 2; ++kt) {
            half8 bh = *(const half8*)(&XhB[xn + col * RS + OFF_H1 + 32 * kt + k0q]);
            half8 bl = *(const half8*)(&XlB[xn + col * RS + OFF_H1 + 32 * kt + k0q]);
            #pragma unroll
            for (int tf = 0; tf < 2; ++tf) {
                accf[tf] = MFMA16(wff[kt][tf], bh, accf[tf]);
                accf[tf] = MFMA16(wff[kt][tf], bl, accf[tf]);
            }
        }

        xc = xn;   // swap buffers (no barrier needed: next P1/P2 touch only regions
                   // whose last cross-wave access is already separated by B_a/B_b)
    }

    // ===== epilogue: reduce step-127 FC accumulator and write the last output =====
    {
        float p = 0.0f;
        #pragma unroll
        for (int tf = 0; tf < 2; ++tf)
            #pragma unroll
            for (int r5 = 0; r5 < 4; ++r5)
                p += w2r[tf][r5] * fmaxf(accf[tf][r5], 0.0f);
        p += __shfl_xor(p, 16);
        p += __shfl_xor(p, 32);
        if (wv == 0 && lane < 16)
            out[(size_t)(b0 + lane) * TSTEPS + (TSTEPS - 1)] = p + bf2;
    }
}

extern "C" void kernel_launch(void* const* d_in, const int* in_sizes, int n_in,
                              void* d_out, int out_size, void* d_ws, size_t ws_size,
                              hipStream_t stream) {
    const float* feat  = (const float*)d_in[0];
    const float* w_ih0 = (const float*)d_in[1];
    const float* w_hh0 = (const float*)d_in[2];
    const float* b_0   = (const float*)d_in[3];
    const float* w_ih1 = (const float*)d_in[4];
    const float* w_hh1 = (const float*)d_in[5];
    const float* b_1   = (const float*)d_in[6];
    const float* w_fc1 = (const float*)d_in[7];
    const float* b_fc1 = (const float*)d_in[8];
    const float* w_fc2 = (const float*)d_in[9];
    const float* b_fc2 = (const float*)d_in[10];
    float* out = (float*)d_out;

    dim3 grid(BATCH / BT);   // 512 blocks x 448 threads; ~38 KB LDS
    dim3 block(NTHREADS);
    hipLaunchKernelGGL(lstm2_w8_kernel, grid, block, 0, stream,
                       feat, w_ih0, w_hh0, b_0, w_ih1, w_hh1, b_1,
                       w_fc1, b_fc1, w_fc2, b_fc2, out);
}